// Round 1
// baseline (408.037 us; speedup 1.0000x reference)
//
#include <hip/hip_runtime.h>
#include <hip/hip_bf16.h>
#include <stdint.h>

#define B_  4
#define S_  2048
#define D_  1024
#define H_  16
#define HD_ 64
#define LOG2E 1.44269504088896f

typedef unsigned short u16;
typedef short bf16x8 __attribute__((ext_vector_type(8)));
typedef float f32x4 __attribute__((ext_vector_type(4)));

static __device__ __forceinline__ u16 f2bf(float f) {
    union { float f; uint32_t u; } v; v.f = f;
    return (u16)((v.u + 0x7FFF + ((v.u >> 16) & 1)) >> 16);
}

// ---------------- weight transpose + bf16 convert: Wt[n][k] = bf16(W[k][n]) ----------------
__global__ __launch_bounds__(256) void wtrans(
    const float* __restrict__ W0, const float* __restrict__ W1, const float* __restrict__ W2,
    u16* __restrict__ T0, u16* __restrict__ T1, u16* __restrict__ T2)
{
    const float* W = blockIdx.z == 0 ? W0 : (blockIdx.z == 1 ? W1 : W2);
    u16* T       = blockIdx.z == 0 ? T0 : (blockIdx.z == 1 ? T1 : T2);
    __shared__ float t[32][33];
    const int n0 = blockIdx.x * 32, k0 = blockIdx.y * 32;
    const int tx = threadIdx.x, ty = threadIdx.y;
#pragma unroll
    for (int i = 0; i < 4; ++i)
        t[ty + i * 8][tx] = W[(size_t)(k0 + ty + i * 8) * D_ + n0 + tx];
    __syncthreads();
#pragma unroll
    for (int i = 0; i < 4; ++i)
        T[(size_t)(n0 + ty + i * 8) * D_ + k0 + tx] = f2bf(t[tx][ty + i * 8]);
}

// ---------------- projection GEMM: Y = X @ Wt^T + b ----------------
// X: (8192, 1024) fp32.  Wt: (1024 out, 1024 in) bf16 (pre-transposed).
// MODE 0: Q -> (B,H,S,HD) bf16, scaled by 0.125
// MODE 1: K -> (B,H,S,HD) bf16
// MODE 2: V -> (B,H,HD,S) bf16 (transposed for NT-form PV)
template <int MODE>
__global__ __launch_bounds__(256) void proj_gemm(
    const float* __restrict__ X, const u16* __restrict__ Wt,
    const float* __restrict__ bias, u16* __restrict__ out)
{
    __shared__ __align__(16) u16 lA[128 * 64];  // [m][k]
    __shared__ __align__(16) u16 lB[128 * 64];  // [n][k]
    const int tid = threadIdx.x;
    const int m0 = blockIdx.x * 128, n0 = blockIdx.y * 128;
    const int w = tid >> 6, lane = tid & 63;
    const int lr = lane & 15, lg = lane >> 4;
    const int wr = (w >> 1) * 64, wc = (w & 1) * 64;

    f32x4 acc[4][4] = {};

    for (int k0 = 0; k0 < D_; k0 += 64) {
        __syncthreads();
        // stage A: fp32 -> bf16 (8192 elems, 8 iters of 256 x float4)
#pragma unroll
        for (int i = 0; i < 8; ++i) {
            const int lin = i * 1024 + tid * 4;
            const int r = lin >> 6, c = lin & 63;
            const float4 v = *(const float4*)(X + (size_t)(m0 + r) * D_ + k0 + c);
            uint2 pk;
            pk.x = (uint32_t)f2bf(v.x) | ((uint32_t)f2bf(v.y) << 16);
            pk.y = (uint32_t)f2bf(v.z) | ((uint32_t)f2bf(v.w) << 16);
            *(uint2*)&lA[lin] = pk;
        }
        // stage B: bf16x8 vector copies (8192 elems, 4 iters of 256 x 16B)
#pragma unroll
        for (int i = 0; i < 4; ++i) {
            const int lin = (i * 256 + tid) * 8;
            const int r = lin >> 6, c = lin & 63;
            *(bf16x8*)&lB[lin] = *(const bf16x8*)(Wt + (size_t)(n0 + r) * D_ + k0 + c);
        }
        __syncthreads();
#pragma unroll
        for (int kk = 0; kk < 64; kk += 32) {
            bf16x8 af[4], bfr[4];
#pragma unroll
            for (int m = 0; m < 4; ++m)
                af[m] = *(const bf16x8*)&lA[(wr + m * 16 + lr) * 64 + kk + lg * 8];
#pragma unroll
            for (int n = 0; n < 4; ++n)
                bfr[n] = *(const bf16x8*)&lB[(wc + n * 16 + lr) * 64 + kk + lg * 8];
#pragma unroll
            for (int m = 0; m < 4; ++m)
#pragma unroll
                for (int n = 0; n < 4; ++n)
                    acc[m][n] = __builtin_amdgcn_mfma_f32_16x16x32_bf16(af[m], bfr[n], acc[m][n], 0, 0, 0);
        }
    }
    // epilogue: bias, (Q scale), write to attention layout
#pragma unroll
    for (int m = 0; m < 4; ++m)
#pragma unroll
        for (int n = 0; n < 4; ++n)
#pragma unroll
            for (int j = 0; j < 4; ++j) {
                const int gm = m0 + wr + m * 16 + lg * 4 + j;  // row in (B*S)
                const int gn = n0 + wc + n * 16 + lr;          // output feature
                float y = acc[m][n][j] + bias[gn];
                if (MODE == 0) y *= 0.125f;  // 1/sqrt(HD), exact in bf16
                const int bb = gm >> 11, s = gm & (S_ - 1);
                const int h = gn >> 6, hd = gn & 63;
                size_t off;
                if (MODE < 2) off = (((size_t)bb * H_ + h) * S_ + s) * HD_ + hd;
                else          off = (((size_t)bb * H_ + h) * HD_ + hd) * S_ + s;
                out[off] = f2bf(y);
            }
}

// ---------------- causal flash attention ----------------
// grid: (S/64, B*H), block 256 (4 waves; wave w owns Q rows [q0+16w, q0+16w+16))
__global__ __launch_bounds__(256) void attn_kernel(
    const u16* __restrict__ qb, const u16* __restrict__ kb,
    const u16* __restrict__ vtb, float* __restrict__ out)
{
    const int bh = blockIdx.y;
    const int b = bh >> 4, h = bh & 15;
    const int q0 = blockIdx.x * 64;
    const int tid = threadIdx.x;
    const int w = tid >> 6, lane = tid & 63;
    const int lr = lane & 15, lg = lane >> 4;

    __shared__ __align__(16) u16 lK[64 * 64];     // [kv][d]
    __shared__ __align__(16) u16 lV[64 * 64];     // [d][kv]  (from V^T)
    __shared__ __align__(16) u16 lP[4][16 * 64];  // per-wave P tile [row][kv]

    // Q fragments, held for whole KV loop (Q pre-scaled by 0.125 in proj)
    const size_t qbase = ((size_t)bh * S_ + q0 + w * 16 + lr) * HD_;
    const bf16x8 qf0 = *(const bf16x8*)(qb + qbase + lg * 8);
    const bf16x8 qf1 = *(const bf16x8*)(qb + qbase + 32 + lg * 8);

    f32x4 oacc[4] = {};
    float m_run[4], l_run[4];
#pragma unroll
    for (int j = 0; j < 4; ++j) { m_run[j] = -1e30f; l_run[j] = 0.f; }

    const size_t kbase = (size_t)bh * S_ * HD_;
    const size_t vbase = (size_t)bh * HD_ * S_;
    const int tmax = q0 >> 6;

    for (int t = 0; t <= tmax; ++t) {
        const int kv0 = t * 64;
        __syncthreads();  // previous tile's PV reads done
        // stage K (rows kv, cols d) and V^T (rows d, cols kv): 2 iters x 256 x 16B each
#pragma unroll
        for (int i = 0; i < 2; ++i) {
            const int lin = (i * 256 + tid) * 8;
            const int r = lin >> 6, c = lin & 63;
            *(bf16x8*)&lK[lin] = *(const bf16x8*)(kb + kbase + (size_t)(kv0 + r) * HD_ + c);
            *(bf16x8*)&lV[lin] = *(const bf16x8*)(vtb + vbase + (size_t)r * S_ + kv0 + c);
        }
        __syncthreads();

        // S = Q K^T  (16x64 strip per wave, 4 col-tiles)
        f32x4 sacc[4];
#pragma unroll
        for (int n = 0; n < 4; ++n) {
            const bf16x8 k0f = *(const bf16x8*)&lK[(n * 16 + lr) * 64 + lg * 8];
            const bf16x8 k1f = *(const bf16x8*)&lK[(n * 16 + lr) * 64 + 32 + lg * 8];
            f32x4 z = {};
            z = __builtin_amdgcn_mfma_f32_16x16x32_bf16(qf0, k0f, z, 0, 0, 0);
            z = __builtin_amdgcn_mfma_f32_16x16x32_bf16(qf1, k1f, z, 0, 0, 0);
            sacc[n] = z;
        }
        // causal mask on diagonal tile (kv0 == q0)
        if (t == tmax) {
#pragma unroll
            for (int n = 0; n < 4; ++n)
#pragma unroll
                for (int j = 0; j < 4; ++j) {
                    const int row_rel = w * 16 + lg * 4 + j;
                    const int col_rel = n * 16 + lr;
                    if (col_rel > row_rel) sacc[n][j] = -1e30f;
                }
        }
        // online softmax (row j lives on the 16 lanes sharing lg)
#pragma unroll
        for (int j = 0; j < 4; ++j) {
            float rm = fmaxf(fmaxf(sacc[0][j], sacc[1][j]), fmaxf(sacc[2][j], sacc[3][j]));
            rm = fmaxf(rm, __shfl_xor(rm, 1));
            rm = fmaxf(rm, __shfl_xor(rm, 2));
            rm = fmaxf(rm, __shfl_xor(rm, 4));
            rm = fmaxf(rm, __shfl_xor(rm, 8));
            const float mn = fmaxf(m_run[j], rm);
            const float alpha = exp2f((m_run[j] - mn) * LOG2E);
            m_run[j] = mn;
            float rs = 0.f;
#pragma unroll
            for (int n = 0; n < 4; ++n) {
                const float p = exp2f((sacc[n][j] - mn) * LOG2E);
                sacc[n][j] = p;
                rs += p;
            }
            rs += __shfl_xor(rs, 1);
            rs += __shfl_xor(rs, 2);
            rs += __shfl_xor(rs, 4);
            rs += __shfl_xor(rs, 8);
            l_run[j] = l_run[j] * alpha + rs;
#pragma unroll
            for (int n = 0; n < 4; ++n) oacc[n][j] *= alpha;
        }
        // P -> LDS (C-layout scatter), then re-fragment as MFMA A-operand
#pragma unroll
        for (int n = 0; n < 4; ++n)
#pragma unroll
            for (int j = 0; j < 4; ++j)
                lP[w][(lg * 4 + j) * 64 + n * 16 + lr] = f2bf(sacc[n][j]);
        __syncthreads();

        const bf16x8 pA0 = *(const bf16x8*)&lP[w][lr * 64 + lg * 8];
        const bf16x8 pA1 = *(const bf16x8*)&lP[w][lr * 64 + 32 + lg * 8];
#pragma unroll
        for (int n = 0; n < 4; ++n) {
            const bf16x8 vf0 = *(const bf16x8*)&lV[(n * 16 + lr) * 64 + lg * 8];
            const bf16x8 vf1 = *(const bf16x8*)&lV[(n * 16 + lr) * 64 + 32 + lg * 8];
            oacc[n] = __builtin_amdgcn_mfma_f32_16x16x32_bf16(pA0, vf0, oacc[n], 0, 0, 0);
            oacc[n] = __builtin_amdgcn_mfma_f32_16x16x32_bf16(pA1, vf1, oacc[n], 0, 0, 0);
        }
    }

    // epilogue: normalize and write (B,S,D) fp32
    float inv[4];
#pragma unroll
    for (int j = 0; j < 4; ++j) inv[j] = 1.f / l_run[j];
#pragma unroll
    for (int n = 0; n < 4; ++n)
#pragma unroll
        for (int j = 0; j < 4; ++j) {
            const int row = q0 + w * 16 + lg * 4 + j;
            out[((size_t)b * S_ + row) * D_ + h * HD_ + n * 16 + lr] = oacc[n][j] * inv[j];
        }
}

extern "C" void kernel_launch(void* const* d_in, const int* in_sizes, int n_in,
                              void* d_out, int out_size, void* d_ws, size_t ws_size,
                              hipStream_t stream) {
    const float* Q  = (const float*)d_in[0];
    const float* K  = (const float*)d_in[1];
    const float* V  = (const float*)d_in[2];
    const float* Wq = (const float*)d_in[3];
    const float* bq = (const float*)d_in[4];
    const float* Wk = (const float*)d_in[5];
    const float* bk = (const float*)d_in[6];
    const float* Wv = (const float*)d_in[7];
    const float* bv = (const float*)d_in[8];
    float* out = (float*)d_out;

    char* ws = (char*)d_ws;
    const size_t WT_BYTES  = (size_t)D_ * D_ * 2;          // 2 MB each
    const size_t QKV_BYTES = (size_t)B_ * S_ * D_ * 2;     // 16 MB each
    u16* Wtq = (u16*)(ws);
    u16* Wtk = (u16*)(ws + WT_BYTES);
    u16* Wtv = (u16*)(ws + 2 * WT_BYTES);
    u16* qb  = (u16*)(ws + 3 * WT_BYTES);
    u16* kb  = (u16*)(ws + 3 * WT_BYTES + QKV_BYTES);
    u16* vtb = (u16*)(ws + 3 * WT_BYTES + 2 * QKV_BYTES);

    wtrans<<<dim3(32, 32, 3), dim3(32, 8), 0, stream>>>(Wq, Wk, Wv, Wtq, Wtk, Wtv);
    proj_gemm<0><<<dim3(64, 8), dim3(256), 0, stream>>>(Q, Wtq, bq, qb);
    proj_gemm<1><<<dim3(64, 8), dim3(256), 0, stream>>>(K, Wtk, bk, kb);
    proj_gemm<2><<<dim3(64, 8), dim3(256), 0, stream>>>(V, Wtv, bv, vtb);
    attn_kernel<<<dim3(S_ / 64, B_ * H_), dim3(256), 0, stream>>>(qb, kb, vtb, out);
}

// Round 2
// 216.675 us; speedup vs baseline: 1.8832x; 1.8832x over previous
//
#include <hip/hip_runtime.h>
#include <hip/hip_bf16.h>
#include <stdint.h>

#define B_  4
#define S_  2048
#define D_  1024
#define H_  16
#define HD_ 64
#define LOG2E 1.44269504088896f

typedef unsigned short u16;
typedef short bf16x8 __attribute__((ext_vector_type(8)));
typedef float f32x4 __attribute__((ext_vector_type(4)));

static __device__ __forceinline__ u16 f2bf(float f) {
    union { float f; uint32_t u; } v; v.f = f;
    return (u16)((v.u + 0x7FFF + ((v.u >> 16) & 1)) >> 16);
}

// Swizzled 16B LDS read from a tile with 128B rows. slot = logical 16B column (0..7).
// Physical layout: byte = row*128 + ((slot ^ (row&7)) << 4)  — T2 st-style XOR swizzle.
static __device__ __forceinline__ bf16x8 rd_swz(const u16* base, int row, int slot) {
    return *(const bf16x8*)((const char*)base + row * 128 + ((slot ^ (row & 7)) << 4));
}

// global -> LDS direct copy (16B/lane) of one 8-row x 128B chunk, with the
// inverse swizzle applied on the GLOBAL side (rule #21: linear LDS dest,
// pre-swizzled source, swizzled reads). lds_chunk = wave-uniform chunk base,
// chunk must start at a row multiple of 8. stride in u16 elements.
static __device__ __forceinline__ void gll_swz(const u16* grow0, size_t stride,
                                               u16* lds_chunk, int lane) {
    const int r = lane >> 3;                 // row within chunk (== abs row & 7)
    const int slot = (lane & 7) ^ r;         // logical slot feeding physical slot lane&7
    const u16* g = grow0 + (size_t)r * stride + slot * 8;
    __builtin_amdgcn_global_load_lds(
        (const __attribute__((address_space(1))) uint32_t*)g,
        (__attribute__((address_space(3))) uint32_t*)lds_chunk, 16, 0, 0);
}

// ---------------- weight transpose + bf16 convert: Wt[n][k] = bf16(W[k][n]) ----------------
__global__ __launch_bounds__(256) void wtrans(
    const float* __restrict__ W0, const float* __restrict__ W1, const float* __restrict__ W2,
    u16* __restrict__ T0, u16* __restrict__ T1, u16* __restrict__ T2)
{
    const float* W = blockIdx.z == 0 ? W0 : (blockIdx.z == 1 ? W1 : W2);
    u16* T       = blockIdx.z == 0 ? T0 : (blockIdx.z == 1 ? T1 : T2);
    __shared__ float t[32][33];
    const int n0 = blockIdx.x * 32, k0 = blockIdx.y * 32;
    const int tx = threadIdx.x, ty = threadIdx.y;
#pragma unroll
    for (int i = 0; i < 4; ++i)
        t[ty + i * 8][tx] = W[(size_t)(k0 + ty + i * 8) * D_ + n0 + tx];
    __syncthreads();
#pragma unroll
    for (int i = 0; i < 4; ++i)
        T[(size_t)(n0 + ty + i * 8) * D_ + k0 + tx] = f2bf(t[tx][ty + i * 8]);
}

// ---------------- projection GEMM: Y = X @ Wt^T + b ----------------
// MODE 0: Q -> (B,H,S,HD) bf16, scaled by 0.125
// MODE 1: K -> (B,H,S,HD) bf16
// MODE 2: V -> (B,H,HD,S) bf16 (transposed for NT-form PV)
template <int MODE>
__global__ __launch_bounds__(256) void proj_gemm(
    const float* __restrict__ X, const u16* __restrict__ Wt,
    const float* __restrict__ bias, u16* __restrict__ out)
{
    __shared__ __align__(16) u16 lA[128 * 64];  // [m][k], swizzled
    __shared__ __align__(16) u16 lB[128 * 64];  // [n][k], swizzled
    const int tid = threadIdx.x;
    const int m0 = blockIdx.x * 128, n0 = blockIdx.y * 128;
    const int w = tid >> 6, lane = tid & 63;
    const int lr = lane & 15, lg = lane >> 4;
    const int wr = (w >> 1) * 64, wc = (w & 1) * 64;

    f32x4 acc[4][4] = {};

    for (int k0 = 0; k0 < D_; k0 += 64) {
        __syncthreads();
        // stage B via global_load_lds (bf16 source): 16 chunks, 4 per wave
#pragma unroll
        for (int i = 0; i < 4; ++i) {
            const int c = w * 4 + i;
            gll_swz(Wt + (size_t)(n0 + c * 8) * D_ + k0, D_, &lB[c * 512], lane);
        }
        // stage A: fp32 -> bf16 reg conversion, swizzled LDS write
#pragma unroll
        for (int i = 0; i < 8; ++i) {
            const int lin = i * 1024 + tid * 4;
            const int r = lin >> 6, c = lin & 63;
            const float4 v = *(const float4*)(X + (size_t)(m0 + r) * D_ + k0 + c);
            uint2 pk;
            pk.x = (uint32_t)f2bf(v.x) | ((uint32_t)f2bf(v.y) << 16);
            pk.y = (uint32_t)f2bf(v.z) | ((uint32_t)f2bf(v.w) << 16);
            const int phys = r * 128 + (((c >> 3) ^ (r & 7)) << 4) + ((c & 7) << 1);
            *(uint2*)((char*)lA + phys) = pk;
        }
        __syncthreads();
#pragma unroll
        for (int kk = 0; kk < 64; kk += 32) {
            bf16x8 af[4], bfr[4];
#pragma unroll
            for (int m = 0; m < 4; ++m)
                af[m] = rd_swz(lA, wr + m * 16 + lr, (kk >> 3) + lg);
#pragma unroll
            for (int n = 0; n < 4; ++n)
                bfr[n] = rd_swz(lB, wc + n * 16 + lr, (kk >> 3) + lg);
#pragma unroll
            for (int m = 0; m < 4; ++m)
#pragma unroll
                for (int n = 0; n < 4; ++n)
                    acc[m][n] = __builtin_amdgcn_mfma_f32_16x16x32_bf16(af[m], bfr[n], acc[m][n], 0, 0, 0);
        }
    }
#pragma unroll
    for (int m = 0; m < 4; ++m)
#pragma unroll
        for (int n = 0; n < 4; ++n)
#pragma unroll
            for (int j = 0; j < 4; ++j) {
                const int gm = m0 + wr + m * 16 + lg * 4 + j;
                const int gn = n0 + wc + n * 16 + lr;
                float y = acc[m][n][j] + bias[gn];
                if (MODE == 0) y *= 0.125f;  // 1/sqrt(64)
                const int bb = gm >> 11, s = gm & (S_ - 1);
                const int h = gn >> 6, hd = gn & 63;
                size_t off;
                if (MODE < 2) off = (((size_t)bb * H_ + h) * S_ + s) * HD_ + hd;
                else          off = (((size_t)bb * H_ + h) * HD_ + hd) * S_ + s;
                out[off] = f2bf(y);
            }
}

// ---------------- causal flash attention ----------------
// grid: (8, B*H), block 512 (8 waves x 16 q-rows = 128-row q-tile).
// Block bx processes q-tile pair (bx, 15-bx): exactly 34 KV-tiles each -> perfect balance.
__global__ __launch_bounds__(512) void attn_kernel(
    const u16* __restrict__ qb, const u16* __restrict__ kb,
    const u16* __restrict__ vtb, float* __restrict__ out)
{
    const int bh = blockIdx.y;
    const int b = bh >> 4, h = bh & 15;
    const int tid = threadIdx.x;
    const int w = tid >> 6, lane = tid & 63;
    const int lr = lane & 15, lg = lane >> 4;

    __shared__ __align__(16) u16 lK[64 * 64];      // [kv][d], swizzled
    __shared__ __align__(16) u16 lV[64 * 64];      // [d][kv], swizzled
    __shared__ __align__(16) u16 lP[8][16 * 64];   // per-wave [row][kv], swizzled

    const size_t kbase = (size_t)bh * S_ * HD_;
    const size_t vbase = (size_t)bh * HD_ * S_;

    for (int e = 0; e < 2; ++e) {
        const int qi = (e == 0) ? blockIdx.x : 15 - blockIdx.x;
        const int q0 = qi * 128;
        const int qrow = q0 + w * 16 + lr;

        const size_t qoff = ((size_t)bh * S_ + qrow) * HD_;
        const bf16x8 qf0 = *(const bf16x8*)(qb + qoff + lg * 8);
        const bf16x8 qf1 = *(const bf16x8*)(qb + qoff + 32 + lg * 8);

        f32x4 oacc[4] = {};
        float m_run[4], l_run[4];
#pragma unroll
        for (int j = 0; j < 4; ++j) { m_run[j] = -1e30f; l_run[j] = 0.f; }

        const int tmax = 2 * qi + 1;
        for (int t = 0; t <= tmax; ++t) {
            const int kv0 = t * 64;
            __syncthreads();  // prior tile's LDS reads done
            // stage K,V: 8 chunks each, 1 K-chunk + 1 V-chunk per wave
            gll_swz(kb + kbase + (size_t)(kv0 + w * 8) * HD_, HD_, &lK[w * 512], lane);
            gll_swz(vtb + vbase + (size_t)(w * 8) * S_ + kv0, S_, &lV[w * 512], lane);
            __syncthreads();  // compiler drains vmcnt before barrier

            // S = Q K^T (16x64 strip per wave)
            f32x4 sacc[4];
#pragma unroll
            for (int n = 0; n < 4; ++n) {
                const bf16x8 k0f = rd_swz(lK, n * 16 + lr, lg);
                const bf16x8 k1f = rd_swz(lK, n * 16 + lr, 4 + lg);
                f32x4 z = {};
                z = __builtin_amdgcn_mfma_f32_16x16x32_bf16(qf0, k0f, z, 0, 0, 0);
                z = __builtin_amdgcn_mfma_f32_16x16x32_bf16(qf1, k1f, z, 0, 0, 0);
                sacc[n] = z;
            }
            // causal mask (only the last two tiles can straddle the diagonal)
            if (t >= tmax - 1) {
#pragma unroll
                for (int n = 0; n < 4; ++n)
#pragma unroll
                    for (int j = 0; j < 4; ++j) {
                        const int row_abs = q0 + w * 16 + lg * 4 + j;
                        const int col_abs = kv0 + n * 16 + lr;
                        if (col_abs > row_abs) sacc[n][j] = -1e30f;
                    }
            }
            // online softmax (row j lives on the 16 lanes sharing lg)
#pragma unroll
            for (int j = 0; j < 4; ++j) {
                float rm = fmaxf(fmaxf(sacc[0][j], sacc[1][j]), fmaxf(sacc[2][j], sacc[3][j]));
                rm = fmaxf(rm, __shfl_xor(rm, 1));
                rm = fmaxf(rm, __shfl_xor(rm, 2));
                rm = fmaxf(rm, __shfl_xor(rm, 4));
                rm = fmaxf(rm, __shfl_xor(rm, 8));
                const float mn = fmaxf(m_run[j], rm);
                const float alpha = exp2f((m_run[j] - mn) * LOG2E);
                m_run[j] = mn;
                float rs = 0.f;
#pragma unroll
                for (int n = 0; n < 4; ++n) {
                    const float p = exp2f((sacc[n][j] - mn) * LOG2E);
                    sacc[n][j] = p;
                    rs += p;
                }
                rs += __shfl_xor(rs, 1);
                rs += __shfl_xor(rs, 2);
                rs += __shfl_xor(rs, 4);
                rs += __shfl_xor(rs, 8);
                l_run[j] = l_run[j] * alpha + rs;
#pragma unroll
                for (int n = 0; n < 4; ++n) oacc[n][j] *= alpha;
            }
            // P -> wave-private LDS (swizzled scalar writes); no barrier needed
#pragma unroll
            for (int n = 0; n < 4; ++n)
#pragma unroll
                for (int j = 0; j < 4; ++j) {
                    const int prow = lg * 4 + j;
                    const int pcol = n * 16 + lr;
                    const int phys = prow * 128 + ((((pcol >> 3) ^ (prow & 7))) << 4) + ((pcol & 7) << 1);
                    *(u16*)((char*)&lP[w][0] + phys) = f2bf(sacc[n][j]);
                }
            const bf16x8 pA0 = rd_swz(&lP[w][0], lr, lg);
            const bf16x8 pA1 = rd_swz(&lP[w][0], lr, 4 + lg);
#pragma unroll
            for (int n = 0; n < 4; ++n) {
                const bf16x8 vf0 = rd_swz(lV, n * 16 + lr, lg);
                const bf16x8 vf1 = rd_swz(lV, n * 16 + lr, 4 + lg);
                oacc[n] = __builtin_amdgcn_mfma_f32_16x16x32_bf16(pA0, vf0, oacc[n], 0, 0, 0);
                oacc[n] = __builtin_amdgcn_mfma_f32_16x16x32_bf16(pA1, vf1, oacc[n], 0, 0, 0);
            }
        }
        // epilogue for this q-tile
        float inv[4];
#pragma unroll
        for (int j = 0; j < 4; ++j) inv[j] = 1.f / l_run[j];
#pragma unroll
        for (int n = 0; n < 4; ++n)
#pragma unroll
            for (int j = 0; j < 4; ++j) {
                const int row = q0 + w * 16 + lg * 4 + j;
                out[((size_t)b * S_ + row) * D_ + h * HD_ + n * 16 + lr] = oacc[n][j] * inv[j];
            }
    }
}

extern "C" void kernel_launch(void* const* d_in, const int* in_sizes, int n_in,
                              void* d_out, int out_size, void* d_ws, size_t ws_size,
                              hipStream_t stream) {
    const float* Q  = (const float*)d_in[0];
    const float* K  = (const float*)d_in[1];
    const float* V  = (const float*)d_in[2];
    const float* Wq = (const float*)d_in[3];
    const float* bq = (const float*)d_in[4];
    const float* Wk = (const float*)d_in[5];
    const float* bk = (const float*)d_in[6];
    const float* Wv = (const float*)d_in[7];
    const float* bv = (const float*)d_in[8];
    float* out = (float*)d_out;

    char* ws = (char*)d_ws;
    const size_t WT_BYTES  = (size_t)D_ * D_ * 2;
    const size_t QKV_BYTES = (size_t)B_ * S_ * D_ * 2;
    u16* Wtq = (u16*)(ws);
    u16* Wtk = (u16*)(ws + WT_BYTES);
    u16* Wtv = (u16*)(ws + 2 * WT_BYTES);
    u16* qb  = (u16*)(ws + 3 * WT_BYTES);
    u16* kb  = (u16*)(ws + 3 * WT_BYTES + QKV_BYTES);
    u16* vtb = (u16*)(ws + 3 * WT_BYTES + 2 * QKV_BYTES);

    wtrans<<<dim3(32, 32, 3), dim3(32, 8), 0, stream>>>(Wq, Wk, Wv, Wtq, Wtk, Wtv);
    proj_gemm<0><<<dim3(64, 8), dim3(256), 0, stream>>>(Q, Wtq, bq, qb);
    proj_gemm<1><<<dim3(64, 8), dim3(256), 0, stream>>>(K, Wtk, bk, kb);
    proj_gemm<2><<<dim3(64, 8), dim3(256), 0, stream>>>(V, Wtv, bv, vtb);
    attn_kernel<<<dim3(8, B_ * H_), dim3(512), 0, stream>>>(qb, kb, vtb, out);
}